// Round 8
// baseline (134.315 us; speedup 1.0000x reference)
//
#include <hip/hip_runtime.h>

#define N1    2001
#define EMB   64
#define NSHOW 5
#define MSONG 25
#define NPOS  (NSHOW * MSONG)   // 125
#define MAXU  128
#define NT    1024
#define WT    68                // transposed-weight row stride: b128 R/W conflict-free

__global__ __launch_bounds__(NT)
__attribute__((amdgpu_waves_per_eu(4, 4)))
void setsgnn_kernel(
    const int* __restrict__ song_ids,
    const int* __restrict__ prev_setlists,
    const int* __restrict__ venue_ids,
    const int* __restrict__ tour_ids,
    const int* __restrict__ country_ids,
    const int* __restrict__ is_festival,
    const int* __restrict__ is_marathon,
    const float* __restrict__ song_emb,
    const float* __restrict__ gcn_w1, const float* __restrict__ gcn_b1,
    const float* __restrict__ gcn_w2, const float* __restrict__ gcn_b2,
    const float* __restrict__ q_w,  const float* __restrict__ q_b,
    const float* __restrict__ k_w,  const float* __restrict__ k_b,
    const float* __restrict__ v_w,  const float* __restrict__ v_b,
    const float* __restrict__ venue_t, const float* __restrict__ tour_t,
    const float* __restrict__ country_t, const float* __restrict__ fest_t,
    const float* __restrict__ mara_t,
    const float* __restrict__ ctx_w, const float* __restrict__ ctx_b,
    const float* __restrict__ p1_w,  const float* __restrict__ p1_b,
    const float* __restrict__ p2_w,  const float* __restrict__ p2_b,
    const float* __restrict__ p3_w,  const float* __restrict__ p3_b,
    float* __restrict__ out)
{
    const int b    = blockIdx.x;
    const int tid  = threadIdx.x;
    const int wv   = tid >> 6;
    const int lane = tid & 63;
    const int col0 = tid & 63;      // weight-staging column
    const int eq0  = tid >> 6;      // weight-staging e-quad

    __shared__ __align__(16) float xb0[MAXU][EMB];     // GCN state, in-place
    __shared__ __align__(16) float wldsT[2][EMB][WT];  // transposed weights
    __shared__ __align__(16) float ctxw_l[56][EMB];
    __shared__ __align__(16) float qw_l[EMB][EMB];
    __shared__ __align__(16) float blds[2][EMB];
    __shared__ __align__(16) float bias_ctx[EMB], bias_q[EMB], bias_k[EMB], bias_v[EMB];
    __shared__ __align__(16) float bias_p1[128], bias_p2[EMB], bias_p3w[EMB];
    __shared__ float bias_p3b;
    __shared__ int   idmap[N1];
    __shared__ int   sl[NPOS];
    __shared__ int   pmap[NPOS];
    __shared__ int   list_ids[MAXU];
    __shared__ float c_us[MAXU][NSHOW];
    __shared__ float occv[MAXU];
    __shared__ float invv[MAXU];
    __shared__ float cntm1[NSHOW];
    __shared__ int   cnt_show[NSHOW];
    __shared__ float invc[NSHOW];
    __shared__ int   U_cnt;
    __shared__ __align__(16) float Xsum[NSHOW][EMB];   // layer Xsums, then show sums
    __shared__ float XW[NSHOW][EMB];
    __shared__ float ctxin[56];
    __shared__ float ctxv[EMB];
    __shared__ float qv[EMB];
    __shared__ float vatt[NSHOW][EMB];
    __shared__ float attnw[NSHOW];
    __shared__ float hbuf[3 * EMB];
    __shared__ float h1b[128];
    __shared__ float partial[NT];

    // ======== P0: issue global loads; init; stage weights/biases ========
    float w1r[4], w2r[4];
    #pragma unroll
    for (int j = 0; j < 4; j++) w1r[j] = gcn_w1[(eq0 * 4 + j) * EMB + col0];
    #pragma unroll
    for (int j = 0; j < 4; j++) w2r[j] = gcn_w2[(eq0 * 4 + j) * EMB + col0];
    const float4 qw4 = ((const float4*)q_w)[tid];
    float4 cw4 = make_float4(0.f, 0.f, 0.f, 0.f);
    if (tid < 896) cw4 = ((const float4*)ctx_w)[tid];
    float4 bb;
    if (tid < 32) bb = (tid < 16) ? ((const float4*)gcn_b1)[tid]
                                  : ((const float4*)gcn_b2)[tid - 16];
    const int slr = (tid < NPOS) ? prev_setlists[b * NPOS + tid] : 0;
    const int sid    = song_ids[b];
    const int vid    = venue_ids[b];
    const int tourid = tour_ids[b];
    const int cid    = country_ids[b];
    const int fid    = is_festival[b];
    const int mid    = is_marathon[b];

    for (int i = tid; i < N1; i += NT) idmap[i] = -1;
    for (int t = tid; t < MAXU * NSHOW; t += NT) ((float*)c_us)[t] = 0.f;
    if (tid < NPOS) sl[tid] = slr;
    if (tid == 0) U_cnt = 0;
    *(float4*)&wldsT[0][col0][eq0 * 4] = make_float4(w1r[0], w1r[1], w1r[2], w1r[3]);
    *(float4*)&wldsT[1][col0][eq0 * 4] = make_float4(w2r[0], w2r[1], w2r[2], w2r[3]);
    ((float4*)qw_l)[tid] = qw4;
    if (tid < 896) ((float4*)ctxw_l)[tid] = cw4;
    if (tid < 32) ((float4*)blds)[tid] = bb;
    {
        int r = tid - 256;
        if (r >= 0 && r < 16)        ((float4*)bias_ctx)[r]       = ((const float4*)ctx_b)[r];
        else if (r >= 16 && r < 32)  ((float4*)bias_q)[r - 16]    = ((const float4*)q_b)[r - 16];
        else if (r >= 32 && r < 48)  ((float4*)bias_k)[r - 32]    = ((const float4*)k_b)[r - 32];
        else if (r >= 48 && r < 64)  ((float4*)bias_v)[r - 48]    = ((const float4*)v_b)[r - 48];
        else if (r >= 64 && r < 96)  ((float4*)bias_p1)[r - 64]   = ((const float4*)p1_b)[r - 64];
        else if (r >= 96 && r < 112) ((float4*)bias_p2)[r - 96]   = ((const float4*)p2_b)[r - 96];
        else if (r >= 112 && r < 128)((float4*)bias_p3w)[r - 112] = ((const float4*)p3_w)[r - 112];
        else if (r == 128)           bias_p3b = p3_b[0];
    }
    __syncthreads();   // B1

    // ======== P1: CAS-claim compaction | cnt_show | ctxin | Xsum-L0 from global ========
    if (tid < NPOS) {
        int id = sl[tid];
        if (id > 0) {
            if (atomicCAS(&idmap[id], -1, -2) == -1) {
                int u = atomicAdd(&U_cnt, 1);
                list_ids[u] = id;
                idmap[id] = u;
            }
        }
    } else if (tid == NPOS) {
        if (atomicCAS(&idmap[sid], -1, -2) == -1) {
            int u = atomicAdd(&U_cnt, 1);
            list_ids[u] = sid;
            idmap[sid] = u;
        }
    }
    if (tid >= 128 && tid < 128 + NSHOW) {
        int s = tid - 128, c = 0;
        for (int i = 0; i < MSONG; i++) c += (sl[s * MSONG + i] > 0) ? 1 : 0;
        cnt_show[s] = c; cntm1[s] = (float)(c - 1);
        invc[s] = 1.f / fmaxf((float)c, 1.f);
    }
    if (tid >= 144 && tid < 200) {
        int e = tid - 144; float val;
        if (e < 16)      val = venue_t[vid * 16 + e];
        else if (e < 32) val = tour_t[tourid * 16 + (e - 16)];
        else if (e < 40) val = country_t[cid * 8 + (e - 32)];
        else if (e < 48) val = fest_t[fid * 8 + (e - 40)];
        else             val = mara_t[mid * 8 + (e - 48)];
        ctxin[e] = val;
    }
    if (wv >= 6 && wv < 11) {   // Xsum-L0 straight from song_emb (x0 rows ARE emb rows)
        int s = wv - 6;
        float acc = 0.f;
        #pragma unroll
        for (int i = 0; i < MSONG; i++) {
            int id = sl[s * MSONG + i];
            if (id > 0) acc += song_emb[id * EMB + lane];
        }
        Xsum[s][lane] = acc;
    }
    __syncthreads();   // B2
    const int U = U_cnt;   // <= 126

    // ======== P2: pmap + c_us | ctx matmul | x0 gather ========
    if (tid < NPOS) {
        int id = sl[tid];
        int pm = (id > 0) ? idmap[id] : -1;
        pmap[tid] = pm;
        if (pm >= 0) atomicAdd(&c_us[pm][tid / MSONG], 1.f);
    }
    if (tid >= 896 && tid < 960) {
        int c = tid - 896;
        float acc = bias_ctx[c];
        #pragma unroll
        for (int e = 0; e < 56; e++) acc += ctxin[e] * ctxw_l[e][c];
        ctxv[c] = acc;
    }
    for (int t = tid; t < MAXU * (EMB / 4); t += NT) {
        int u = t >> 4, e4 = t & 15;
        float4 v = make_float4(0.f, 0.f, 0.f, 0.f);
        if (u < U) v = ((const float4*)(song_emb + list_ids[u] * EMB))[e4];
        *(float4*)&xb0[u][e4 * 4] = v;
    }
    __syncthreads();   // B3

    float y[8];
    #define Y_COMPUTE(L)                                                         \
    {                                                                            \
        _Pragma("unroll")                                                        \
        for (int uu = 0; uu < 8; ++uu) y[uu] = 0.f;                              \
        _Pragma("unroll")                                                        \
        for (int e4 = 0; e4 < 16; ++e4) {                                        \
            float4 a[8];                                                         \
            _Pragma("unroll")                                                    \
            for (int uu = 0; uu < 8; ++uu)                                       \
                a[uu] = *(const float4*)&xb0[(uu << 4) | wv][e4 * 4];            \
            const float4 w4 = *(const float4*)&wldsT[L][lane][e4 * 4];           \
            _Pragma("unroll")                                                    \
            for (int uu = 0; uu < 8; ++uu)                                       \
                y[uu] += a[uu].x * w4.x + a[uu].y * w4.y                         \
                       + a[uu].z * w4.z + a[uu].w * w4.w;                        \
        }                                                                        \
    }
    #define COMBINE(L)                                                           \
    {                                                                            \
        const float bias = blds[L][lane];                                        \
        _Pragma("unroll")                                                        \
        for (int uu = 0; uu < 8; ++uu) {                                         \
            const int u = (uu << 4) | wv;                                        \
            float acc = c_us[u][0] * XW[0][lane] + c_us[u][1] * XW[1][lane]      \
                      + c_us[u][2] * XW[2][lane] + c_us[u][3] * XW[3][lane]      \
                      + c_us[u][4] * XW[4][lane];                                \
            float val = (acc - occv[u] * y[uu]) * invv[u] + bias;                \
            xb0[u][lane] = fmaxf(val, 0.f);                                      \
        }                                                                        \
    }

    // ======== P3: occ/inv | q | XW-L0 | y-L0 (all waves) ========
    if (tid < MAXU) {
        float o = 0.f, r = 0.f;
        #pragma unroll
        for (int s = 0; s < NSHOW; s++) { float cc = c_us[tid][s]; o += cc; r += cc * cntm1[s]; }
        occv[tid] = o; invv[tid] = 1.f / (r + 1e-10f);
    }
    if (tid >= 128 && tid < 192) {
        int c = tid - 128;
        float acc = bias_q[c];
        #pragma unroll
        for (int e = 0; e < EMB; e++) acc += ctxv[e] * qw_l[e][c];
        qv[c] = acc;
    }
    if (tid >= 192 && tid < 192 + NSHOW * EMB) {
        int t = tid - 192, s = t >> 6, c = t & 63;
        float acc = 0.f;
        #pragma unroll
        for (int e4 = 0; e4 < 16; e4++) {
            const float4 w4 = *(const float4*)&wldsT[0][c][e4 * 4];
            const float4 xs = *(const float4*)&Xsum[s][e4 * 4];
            acc += w4.x * xs.x + w4.y * xs.y + w4.z * xs.z + w4.w * xs.w;
        }
        XW[s][c] = acc;
    }
    Y_COMPUTE(0)
    __syncthreads();   // B4

    // ======== P4: combine L0 (in-place write) ========
    COMBINE(0)
    __syncthreads();   // B5

    // ======== P5: Xsum-L1 (waves 6-10) | y-L1 (all waves) ========
    if (wv >= 6 && wv < 11) {
        int s = wv - 6;
        int pm[MSONG];
        #pragma unroll
        for (int i = 0; i < MSONG; i++) pm[i] = pmap[s * MSONG + i];
        float acc = 0.f;
        #pragma unroll
        for (int i = 0; i < MSONG; i++) if (pm[i] >= 0) acc += xb0[pm[i]][lane];
        Xsum[s][lane] = acc;
    }
    Y_COMPUTE(1)
    __syncthreads();   // B6

    // ======== P6: XW-L1 ========
    if (tid >= 192 && tid < 192 + NSHOW * EMB) {
        int t = tid - 192, s = t >> 6, c = t & 63;
        float acc = 0.f;
        #pragma unroll
        for (int e4 = 0; e4 < 16; e4++) {
            const float4 w4 = *(const float4*)&wldsT[1][c][e4 * 4];
            const float4 xs = *(const float4*)&Xsum[s][e4 * 4];
            acc += w4.x * xs.x + w4.y * xs.y + w4.z * xs.z + w4.w * xs.w;
        }
        XW[s][c] = acc;
    }
    __syncthreads();   // B7

    // ======== P7: combine L1 ========
    COMBINE(1)
    __syncthreads();   // B8

    // ======== P8: prefetch k/v/p1/p2 | show sums | hbuf cand+ctx | k/v restage ========
    float kvr[8];
    #pragma unroll
    for (int j = 0; j < 4; j++) kvr[j]     = k_w[(eq0 * 4 + j) * EMB + col0];
    #pragma unroll
    for (int j = 0; j < 4; j++) kvr[4 + j] = v_w[(eq0 * 4 + j) * EMB + col0];
    const int kk1 = tid >> 7, o1 = tid & 127;
    const int kk2 = tid >> 6, o2 = lane;
    float p1wr[24], p2wr[8];
    #pragma unroll
    for (int j = 0; j < 24; j++) p1wr[j] = p1_w[(kk1 * 24 + j) * 128 + o1];
    #pragma unroll
    for (int j = 0; j < 8; j++)  p2wr[j] = p2_w[(kk2 * 8 + j) * 64 + o2];

    if (wv >= 6 && wv < 11) {   // show sums (reuse Xsum)
        int s = wv - 6;
        int pm[MSONG];
        #pragma unroll
        for (int i = 0; i < MSONG; i++) pm[i] = pmap[s * MSONG + i];
        float acc = 0.f;
        #pragma unroll
        for (int i = 0; i < MSONG; i++) if (pm[i] >= 0) acc += xb0[pm[i]][lane];
        Xsum[s][lane] = acc;
    }
    if (tid < 64)                    hbuf[tid] = xb0[idmap[sid]][tid];
    else if (tid >= 64 && tid < 128) hbuf[tid] = ctxv[tid - 64];
    *(float4*)&wldsT[0][col0][eq0 * 4] = make_float4(kvr[0], kvr[1], kvr[2], kvr[3]);
    *(float4*)&wldsT[1][col0][eq0 * 4] = make_float4(kvr[4], kvr[5], kvr[6], kvr[7]);
    __syncthreads();   // B9

    // ======== P9: K·q -> scores (waves 0-4) | V (waves 5-9) ========
    if (wv < NSHOW) {
        float s0 = 0.f;
        #pragma unroll
        for (int e4 = 0; e4 < 16; e4++) {
            const float4 w4 = *(const float4*)&wldsT[0][lane][e4 * 4];
            const float4 xs = *(const float4*)&Xsum[wv][e4 * 4];
            s0 += w4.x * xs.x + w4.y * xs.y + w4.z * xs.z + w4.w * xs.w;
        }
        float kk = s0 * invc[wv] + bias_k[lane];
        float p = kk * qv[lane];
        #pragma unroll
        for (int o = 32; o > 0; o >>= 1) p += __shfl_xor(p, o, 64);
        if (lane == 0) attnw[wv] = p * 0.125f;
    }
    if (wv >= 5 && wv < 10) {
        int s = wv - 5;
        float s0 = 0.f;
        #pragma unroll
        for (int e4 = 0; e4 < 16; e4++) {
            const float4 w4 = *(const float4*)&wldsT[1][lane][e4 * 4];
            const float4 xs = *(const float4*)&Xsum[s][e4 * 4];
            s0 += w4.x * xs.x + w4.y * xs.y + w4.z * xs.z + w4.w * xs.w;
        }
        vatt[s][lane] = s0 * invc[s] + bias_v[lane];
    }
    __syncthreads();   // B10

    // ======== P10: wave0 per-lane softmax + attended ========
    if (wv == 0) {
        float a0 = attnw[0], a1 = attnw[1], a2 = attnw[2], a3 = attnw[3], a4 = attnw[4];
        float mx = fmaxf(fmaxf(fmaxf(a0, a1), fmaxf(a2, a3)), a4);
        float e0 = expf(a0 - mx), e1 = expf(a1 - mx), e2 = expf(a2 - mx),
              e3 = expf(a3 - mx), e4 = expf(a4 - mx);
        float isum = 1.f / (e0 + e1 + e2 + e3 + e4);
        float att = (e0 * vatt[0][lane] + e1 * vatt[1][lane] + e2 * vatt[2][lane]
                   + e3 * vatt[3][lane] + e4 * vatt[4][lane]) * isum;
        hbuf[2 * EMB + lane] = att;
    }
    __syncthreads();   // B11

    // ======== P11: p1 partial (split-k 8) ========
    {
        float acc = (kk1 == 0) ? bias_p1[o1] : 0.f;
        #pragma unroll
        for (int j = 0; j < 24; j++) acc += hbuf[kk1 * 24 + j] * p1wr[j];
        partial[tid] = acc;
    }
    __syncthreads();   // B12

    // ======== P12: p1 reduce ========
    if (tid < 128) {
        float acc = 0.f;
        #pragma unroll
        for (int kk = 0; kk < 8; kk++) acc += partial[kk * 128 + tid];
        h1b[tid] = fmaxf(acc, 0.f);
    }
    __syncthreads();   // B13

    // ======== P13: p2 partial (split-k 16) ========
    {
        float acc = (kk2 == 0) ? bias_p2[o2] : 0.f;
        #pragma unroll
        for (int j = 0; j < 8; j++) acc += h1b[kk2 * 8 + j] * p2wr[j];
        partial[tid] = acc;
    }
    __syncthreads();   // B14

    // ======== P14: wave0 p2 reduce + p3 + sigmoid ========
    if (wv == 0) {
        float acc = 0.f;
        #pragma unroll
        for (int kk = 0; kk < 16; kk++) acc += partial[kk * 64 + lane];
        float h2 = fmaxf(acc, 0.f);
        float p = h2 * bias_p3w[lane];
        #pragma unroll
        for (int o = 32; o > 0; o >>= 1) p += __shfl_xor(p, o, 64);
        if (lane == 0) out[b] = 1.f / (1.f + expf(-(p + bias_p3b)));
    }
}

extern "C" void kernel_launch(void* const* d_in, const int* in_sizes, int n_in,
                              void* d_out, int out_size, void* d_ws, size_t ws_size,
                              hipStream_t stream) {
    (void)n_in; (void)out_size; (void)d_ws; (void)ws_size;
    const int B = in_sizes[0];
    setsgnn_kernel<<<B, NT, 0, stream>>>(
        (const int*)d_in[0], (const int*)d_in[1], (const int*)d_in[2],
        (const int*)d_in[3], (const int*)d_in[4], (const int*)d_in[5],
        (const int*)d_in[6],
        (const float*)d_in[7],
        (const float*)d_in[8],  (const float*)d_in[9],
        (const float*)d_in[10], (const float*)d_in[11],
        (const float*)d_in[12], (const float*)d_in[13],
        (const float*)d_in[14], (const float*)d_in[15],
        (const float*)d_in[16], (const float*)d_in[17],
        (const float*)d_in[18], (const float*)d_in[19],
        (const float*)d_in[20], (const float*)d_in[21],
        (const float*)d_in[22],
        (const float*)d_in[23], (const float*)d_in[24],
        (const float*)d_in[25], (const float*)d_in[26],
        (const float*)d_in[27], (const float*)d_in[28],
        (const float*)d_in[29], (const float*)d_in[30],
        (float*)d_out);
}

// Round 9
// 33.670 us; speedup vs baseline: 3.9891x; 3.9891x over previous
//
#include <hip/hip_runtime.h>

#define N1    2001
#define EMB   64
#define NSHOW 5
#define MSONG 25
#define NPOS  (NSHOW * MSONG)   // 125
#define MAXU  128
#define NT    1024
#define WT    68                // transposed-weight row stride: b128 R/W conflict-free

__global__ __launch_bounds__(NT)
__attribute__((amdgpu_waves_per_eu(4, 4)))
void setsgnn_kernel(
    const int* __restrict__ song_ids,
    const int* __restrict__ prev_setlists,
    const int* __restrict__ venue_ids,
    const int* __restrict__ tour_ids,
    const int* __restrict__ country_ids,
    const int* __restrict__ is_festival,
    const int* __restrict__ is_marathon,
    const float* __restrict__ song_emb,
    const float* __restrict__ gcn_w1, const float* __restrict__ gcn_b1,
    const float* __restrict__ gcn_w2, const float* __restrict__ gcn_b2,
    const float* __restrict__ q_w,  const float* __restrict__ q_b,
    const float* __restrict__ k_w,  const float* __restrict__ k_b,
    const float* __restrict__ v_w,  const float* __restrict__ v_b,
    const float* __restrict__ venue_t, const float* __restrict__ tour_t,
    const float* __restrict__ country_t, const float* __restrict__ fest_t,
    const float* __restrict__ mara_t,
    const float* __restrict__ ctx_w, const float* __restrict__ ctx_b,
    const float* __restrict__ p1_w,  const float* __restrict__ p1_b,
    const float* __restrict__ p2_w,  const float* __restrict__ p2_b,
    const float* __restrict__ p3_w,  const float* __restrict__ p3_b,
    float* __restrict__ out)
{
    const int b    = blockIdx.x;
    const int tid  = threadIdx.x;
    const int wv   = tid >> 6;
    const int lane = tid & 63;
    const int col0 = tid & 63;      // weight-staging column
    const int eq0  = tid >> 6;      // weight-staging e-quad

    __shared__ __align__(16) float xb0[MAXU][EMB];     // GCN state, in-place
    __shared__ __align__(16) float wldsT[2][EMB][WT];  // transposed weights (then k,v)
    __shared__ __align__(16) float blds[2][EMB];
    __shared__ __align__(16) float bias_ctx[EMB], bias_q[EMB], bias_k[EMB], bias_v[EMB];
    __shared__ __align__(16) float bias_p1[128], bias_p2[EMB], bias_p3w[EMB];
    __shared__ float bias_p3b;
    __shared__ int   idmap[N1];
    __shared__ int   sl[NPOS];
    __shared__ int   pmap[NPOS];
    __shared__ int   list_ids[MAXU];
    __shared__ float c_us[MAXU][NSHOW];
    __shared__ float occv[MAXU];
    __shared__ float invv[MAXU];
    __shared__ float cntm1[NSHOW];
    __shared__ float invc[NSHOW];
    __shared__ int   U_cnt;
    __shared__ __align__(16) float Xsum[NSHOW][EMB];   // layer Xsums, then show sums
    __shared__ float XW[NSHOW][EMB];
    __shared__ float ctxin[56];
    __shared__ float ctxv[EMB];
    __shared__ float qv[EMB];
    __shared__ float vatt[NSHOW][EMB];
    __shared__ float attnw[NSHOW];
    __shared__ float hbuf[3 * EMB];
    __shared__ float h1b[128];
    __shared__ float partial[NT];

    // ======== P0: coalesced column-strided weight loads; init; stage ========
    float w1r[4], w2r[4];
    #pragma unroll
    for (int j = 0; j < 4; j++) w1r[j] = gcn_w1[(eq0 * 4 + j) * EMB + col0];
    #pragma unroll
    for (int j = 0; j < 4; j++) w2r[j] = gcn_w2[(eq0 * 4 + j) * EMB + col0];
    float4 bb;
    if (tid < 32) bb = (tid < 16) ? ((const float4*)gcn_b1)[tid]
                                  : ((const float4*)gcn_b2)[tid - 16];
    const int slr = (tid < NPOS) ? prev_setlists[b * NPOS + tid] : 0;
    const int sid    = song_ids[b];
    const int vid    = venue_ids[b];
    const int tourid = tour_ids[b];
    const int cid    = country_ids[b];
    const int fid    = is_festival[b];
    const int mid    = is_marathon[b];

    for (int i = tid; i < N1; i += NT) idmap[i] = -1;
    if (tid < MAXU * NSHOW) ((float*)c_us)[tid] = 0.f;
    if (tid < NPOS) sl[tid] = slr;
    if (tid == 0) U_cnt = 0;
    *(float4*)&wldsT[0][col0][eq0 * 4] = make_float4(w1r[0], w1r[1], w1r[2], w1r[3]);
    *(float4*)&wldsT[1][col0][eq0 * 4] = make_float4(w2r[0], w2r[1], w2r[2], w2r[3]);
    if (tid < 32) ((float4*)blds)[tid] = bb;
    {
        int r = tid - 256;
        if (r >= 0 && r < 16)        ((float4*)bias_ctx)[r]       = ((const float4*)ctx_b)[r];
        else if (r >= 16 && r < 32)  ((float4*)bias_q)[r - 16]    = ((const float4*)q_b)[r - 16];
        else if (r >= 32 && r < 48)  ((float4*)bias_k)[r - 32]    = ((const float4*)k_b)[r - 32];
        else if (r >= 48 && r < 64)  ((float4*)bias_v)[r - 48]    = ((const float4*)v_b)[r - 48];
        else if (r >= 64 && r < 96)  ((float4*)bias_p1)[r - 64]   = ((const float4*)p1_b)[r - 64];
        else if (r >= 96 && r < 112) ((float4*)bias_p2)[r - 96]   = ((const float4*)p2_b)[r - 96];
        else if (r >= 112 && r < 128)((float4*)bias_p3w)[r - 112] = ((const float4*)p3_w)[r - 112];
        else if (r == 128)           bias_p3b = p3_b[0];
    }
    __syncthreads();   // B1

    // ======== P1: CAS compaction | cnt_show | ctxin | Xsum-L0 from global ========
    if (tid < NPOS) {
        int id = sl[tid];
        if (id > 0) {
            if (atomicCAS(&idmap[id], -1, -2) == -1) {
                int u = atomicAdd(&U_cnt, 1);
                list_ids[u] = id;
                idmap[id] = u;
            }
        }
    } else if (tid == NPOS) {
        if (atomicCAS(&idmap[sid], -1, -2) == -1) {
            int u = atomicAdd(&U_cnt, 1);
            list_ids[u] = sid;
            idmap[sid] = u;
        }
    }
    if (tid >= 128 && tid < 128 + NSHOW) {
        int s = tid - 128, c = 0;
        for (int i = 0; i < MSONG; i++) c += (sl[s * MSONG + i] > 0) ? 1 : 0;
        cntm1[s] = (float)(c - 1);
        invc[s] = 1.f / fmaxf((float)c, 1.f);
    }
    if (tid >= 144 && tid < 200) {
        int e = tid - 144; float val;
        if (e < 16)      val = venue_t[vid * 16 + e];
        else if (e < 32) val = tour_t[tourid * 16 + (e - 16)];
        else if (e < 40) val = country_t[cid * 8 + (e - 32)];
        else if (e < 48) val = fest_t[fid * 8 + (e - 40)];
        else             val = mara_t[mid * 8 + (e - 48)];
        ctxin[e] = val;
    }
    if (wv >= 6 && wv < 11) {   // Xsum-L0 straight from song_emb (x0 rows ARE emb rows)
        int s = wv - 6;
        float acc = 0.f;
        #pragma unroll
        for (int i = 0; i < MSONG; i++) {
            int id = sl[s * MSONG + i];
            if (id > 0) acc += song_emb[id * EMB + lane];
        }
        Xsum[s][lane] = acc;
    }
    __syncthreads();   // B2
    const int U = U_cnt;   // <= 126

    // ======== P2: pmap + c_us | ctx matmul (global weights) | x0 gather ========
    if (tid < NPOS) {
        int id = sl[tid];
        int pm = (id > 0) ? idmap[id] : -1;
        pmap[tid] = pm;
        if (pm >= 0) atomicAdd(&c_us[pm][tid / MSONG], 1.f);
    }
    if (tid >= 896 && tid < 960) {
        int c = tid - 896;
        float acc = bias_ctx[c];
        #pragma unroll
        for (int e = 0; e < 56; e++) acc += ctxin[e] * ctx_w[e * EMB + c];
        ctxv[c] = acc;
    }
    for (int t = tid; t < MAXU * (EMB / 4); t += NT) {
        int u = t >> 4, e4 = t & 15;
        float4 v = make_float4(0.f, 0.f, 0.f, 0.f);
        if (u < U) v = ((const float4*)(song_emb + list_ids[u] * EMB))[e4];
        *(float4*)&xb0[u][e4 * 4] = v;
    }
    __syncthreads();   // B3

    // ======== P3: occ/inv | q (global weights) | XW-L0 ========
    if (tid < MAXU) {
        float o = 0.f, r = 0.f;
        #pragma unroll
        for (int s = 0; s < NSHOW; s++) { float cc = c_us[tid][s]; o += cc; r += cc * cntm1[s]; }
        occv[tid] = o; invv[tid] = 1.f / (r + 1e-10f);
    }
    if (tid >= 128 && tid < 192) {
        int c = tid - 128;
        float acc = bias_q[c];
        #pragma unroll
        for (int e = 0; e < EMB; e++) acc += ctxv[e] * q_w[e * EMB + c];
        qv[c] = acc;
    }
    if (tid >= 192 && tid < 192 + NSHOW * EMB) {
        int t = tid - 192, s = t >> 6, c = t & 63;
        float acc = 0.f;
        #pragma unroll 4
        for (int e4 = 0; e4 < 16; e4++) {
            const float4 w4 = *(const float4*)&wldsT[0][c][e4 * 4];
            const float4 xs = *(const float4*)&Xsum[s][e4 * 4];
            acc += w4.x * xs.x + w4.y * xs.y + w4.z * xs.z + w4.w * xs.w;
        }
        XW[s][c] = acc;
    }
    __syncthreads();   // B4

    // GCN phase bodies: each wave owns rows u ≡ wv (mod 16) — reads only its
    // own rows in Y, writes only its own rows in COMBINE -> in-place safe.
    #define GCN_BODY(L)                                                          \
    {                                                                            \
        const float bias = blds[L][lane];                                        \
        float y[8];                                                              \
        _Pragma("unroll")                                                        \
        for (int uu = 0; uu < 8; ++uu) y[uu] = 0.f;                              \
        _Pragma("unroll 4")                                                      \
        for (int e4 = 0; e4 < 16; ++e4) {                                        \
            float4 a[8];                                                         \
            _Pragma("unroll")                                                    \
            for (int uu = 0; uu < 8; ++uu)                                       \
                a[uu] = *(const float4*)&xb0[(uu << 4) | wv][e4 * 4];            \
            const float4 w4 = *(const float4*)&wldsT[L][lane][e4 * 4];           \
            _Pragma("unroll")                                                    \
            for (int uu = 0; uu < 8; ++uu)                                       \
                y[uu] += a[uu].x * w4.x + a[uu].y * w4.y                         \
                       + a[uu].z * w4.z + a[uu].w * w4.w;                        \
        }                                                                        \
        _Pragma("unroll")                                                        \
        for (int uu = 0; uu < 8; ++uu) {                                         \
            const int u = (uu << 4) | wv;                                        \
            float acc = c_us[u][0] * XW[0][lane] + c_us[u][1] * XW[1][lane]      \
                      + c_us[u][2] * XW[2][lane] + c_us[u][3] * XW[3][lane]      \
                      + c_us[u][4] * XW[4][lane];                                \
            float val = (acc - occv[u] * y[uu]) * invv[u] + bias;                \
            xb0[u][lane] = fmaxf(val, 0.f);                                      \
        }                                                                        \
    }

    // ======== P4: GCN layer 0 (Y + COMBINE fused) ========
    GCN_BODY(0)
    __syncthreads();   // B5

    // ======== P5: Xsum-L1 (waves 6-10) | k restage into wldsT[0] (dead) ========
    {
        float kr[4];
        #pragma unroll
        for (int j = 0; j < 4; j++) kr[j] = k_w[(eq0 * 4 + j) * EMB + col0];
        if (wv >= 6 && wv < 11) {
            int s = wv - 6;
            int pm[MSONG];
            #pragma unroll
            for (int i = 0; i < MSONG; i++) pm[i] = pmap[s * MSONG + i];
            float acc = 0.f;
            #pragma unroll
            for (int i = 0; i < MSONG; i++) if (pm[i] >= 0) acc += xb0[pm[i]][lane];
            Xsum[s][lane] = acc;
        }
        *(float4*)&wldsT[0][col0][eq0 * 4] = make_float4(kr[0], kr[1], kr[2], kr[3]);
    }
    __syncthreads();   // B6

    // ======== P6: XW-L1 ========
    if (tid >= 192 && tid < 192 + NSHOW * EMB) {
        int t = tid - 192, s = t >> 6, c = t & 63;
        float acc = 0.f;
        #pragma unroll 4
        for (int e4 = 0; e4 < 16; e4++) {
            const float4 w4 = *(const float4*)&wldsT[1][c][e4 * 4];
            const float4 xs = *(const float4*)&Xsum[s][e4 * 4];
            acc += w4.x * xs.x + w4.y * xs.y + w4.z * xs.z + w4.w * xs.w;
        }
        XW[s][c] = acc;
    }
    __syncthreads();   // B7

    // ======== P7: GCN layer 1 + issue v load (write deferred past B8) ========
    float vr[4];
    #pragma unroll
    for (int j = 0; j < 4; j++) vr[j] = v_w[(eq0 * 4 + j) * EMB + col0];
    GCN_BODY(1)
    __syncthreads();   // B8

    // ======== P8: v restage | show sums | hbuf cand+ctx | p1/p2 prefetch ========
    *(float4*)&wldsT[1][col0][eq0 * 4] = make_float4(vr[0], vr[1], vr[2], vr[3]);
    const int kk1 = tid >> 7, o1 = tid & 127;
    const int kk2 = tid >> 6, o2 = lane;
    float p1wr[24], p2wr[8];
    #pragma unroll
    for (int j = 0; j < 24; j++) p1wr[j] = p1_w[(kk1 * 24 + j) * 128 + o1];
    #pragma unroll
    for (int j = 0; j < 8; j++)  p2wr[j] = p2_w[(kk2 * 8 + j) * 64 + o2];

    if (wv >= 6 && wv < 11) {   // show SUMS (invc applied in K/V phase)
        int s = wv - 6;
        int pm[MSONG];
        #pragma unroll
        for (int i = 0; i < MSONG; i++) pm[i] = pmap[s * MSONG + i];
        float acc = 0.f;
        #pragma unroll
        for (int i = 0; i < MSONG; i++) if (pm[i] >= 0) acc += xb0[pm[i]][lane];
        Xsum[s][lane] = acc;
    }
    if (tid < 64)                    hbuf[tid] = xb0[idmap[sid]][tid];
    else if (tid >= 64 && tid < 128) hbuf[tid] = ctxv[tid - 64];
    __syncthreads();   // B9

    // ======== P9: K·q -> scores (waves 0-4) | V (waves 5-9) ========
    if (wv < NSHOW) {
        float s0 = 0.f;
        #pragma unroll 4
        for (int e4 = 0; e4 < 16; e4++) {
            const float4 w4 = *(const float4*)&wldsT[0][lane][e4 * 4];
            const float4 xs = *(const float4*)&Xsum[wv][e4 * 4];
            s0 += w4.x * xs.x + w4.y * xs.y + w4.z * xs.z + w4.w * xs.w;
        }
        float kk = s0 * invc[wv] + bias_k[lane];
        float p = kk * qv[lane];
        #pragma unroll
        for (int o = 32; o > 0; o >>= 1) p += __shfl_xor(p, o, 64);
        if (lane == 0) attnw[wv] = p * 0.125f;
    }
    if (wv >= 5 && wv < 10) {
        int s = wv - 5;
        float s0 = 0.f;
        #pragma unroll 4
        for (int e4 = 0; e4 < 16; e4++) {
            const float4 w4 = *(const float4*)&wldsT[1][lane][e4 * 4];
            const float4 xs = *(const float4*)&Xsum[s][e4 * 4];
            s0 += w4.x * xs.x + w4.y * xs.y + w4.z * xs.z + w4.w * xs.w;
        }
        vatt[s][lane] = s0 * invc[s] + bias_v[lane];
    }
    __syncthreads();   // B10

    // ======== P10: wave0 per-lane softmax + attended ========
    if (wv == 0) {
        float a0 = attnw[0], a1 = attnw[1], a2 = attnw[2], a3 = attnw[3], a4 = attnw[4];
        float mx = fmaxf(fmaxf(fmaxf(a0, a1), fmaxf(a2, a3)), a4);
        float e0 = expf(a0 - mx), e1 = expf(a1 - mx), e2 = expf(a2 - mx),
              e3 = expf(a3 - mx), e4 = expf(a4 - mx);
        float isum = 1.f / (e0 + e1 + e2 + e3 + e4);
        float att = (e0 * vatt[0][lane] + e1 * vatt[1][lane] + e2 * vatt[2][lane]
                   + e3 * vatt[3][lane] + e4 * vatt[4][lane]) * isum;
        hbuf[2 * EMB + lane] = att;
    }
    __syncthreads();   // B11

    // ======== P11: p1 partial (split-k 8) ========
    {
        float acc = (kk1 == 0) ? bias_p1[o1] : 0.f;
        #pragma unroll
        for (int j = 0; j < 24; j++) acc += hbuf[kk1 * 24 + j] * p1wr[j];
        partial[tid] = acc;
    }
    __syncthreads();   // B12

    // ======== P12: p1 reduce ========
    if (tid < 128) {
        float acc = 0.f;
        #pragma unroll
        for (int kk = 0; kk < 8; kk++) acc += partial[kk * 128 + tid];
        h1b[tid] = fmaxf(acc, 0.f);
    }
    __syncthreads();   // B13

    // ======== P13: p2 partial (split-k 16) ========
    {
        float acc = (kk2 == 0) ? bias_p2[o2] : 0.f;
        #pragma unroll
        for (int j = 0; j < 8; j++) acc += h1b[kk2 * 8 + j] * p2wr[j];
        partial[tid] = acc;
    }
    __syncthreads();   // B14

    // ======== P14: wave0 p2 reduce + p3 + sigmoid ========
    if (wv == 0) {
        float acc = 0.f;
        #pragma unroll
        for (int kk = 0; kk < 16; kk++) acc += partial[kk * 64 + lane];
        float h2 = fmaxf(acc, 0.f);
        float p = h2 * bias_p3w[lane];
        #pragma unroll
        for (int o = 32; o > 0; o >>= 1) p += __shfl_xor(p, o, 64);
        if (lane == 0) out[b] = 1.f / (1.f + expf(-(p + bias_p3b)));
    }
}

extern "C" void kernel_launch(void* const* d_in, const int* in_sizes, int n_in,
                              void* d_out, int out_size, void* d_ws, size_t ws_size,
                              hipStream_t stream) {
    (void)n_in; (void)out_size; (void)d_ws; (void)ws_size;
    const int B = in_sizes[0];
    setsgnn_kernel<<<B, NT, 0, stream>>>(
        (const int*)d_in[0], (const int*)d_in[1], (const int*)d_in[2],
        (const int*)d_in[3], (const int*)d_in[4], (const int*)d_in[5],
        (const int*)d_in[6],
        (const float*)d_in[7],
        (const float*)d_in[8],  (const float*)d_in[9],
        (const float*)d_in[10], (const float*)d_in[11],
        (const float*)d_in[12], (const float*)d_in[13],
        (const float*)d_in[14], (const float*)d_in[15],
        (const float*)d_in[16], (const float*)d_in[17],
        (const float*)d_in[18], (const float*)d_in[19],
        (const float*)d_in[20], (const float*)d_in[21],
        (const float*)d_in[22],
        (const float*)d_in[23], (const float*)d_in[24],
        (const float*)d_in[25], (const float*)d_in[26],
        (const float*)d_in[27], (const float*)d_in[28],
        (const float*)d_in[29], (const float*)d_in[30],
        (float*)d_out);
}

// Round 10
// 32.729 us; speedup vs baseline: 4.1038x; 1.0288x over previous
//
#include <hip/hip_runtime.h>

#define N1    2001
#define EMB   64
#define NSHOW 5
#define MSONG 25
#define NPOS  (NSHOW * MSONG)   // 125
#define MAXU  128
#define NT    1024
#define WT    68                // transposed-weight row stride

__global__ __launch_bounds__(NT)
__attribute__((amdgpu_waves_per_eu(4, 4)))
void setsgnn_kernel(
    const int* __restrict__ song_ids,
    const int* __restrict__ prev_setlists,
    const int* __restrict__ venue_ids,
    const int* __restrict__ tour_ids,
    const int* __restrict__ country_ids,
    const int* __restrict__ is_festival,
    const int* __restrict__ is_marathon,
    const float* __restrict__ song_emb,
    const float* __restrict__ gcn_w1, const float* __restrict__ gcn_b1,
    const float* __restrict__ gcn_w2, const float* __restrict__ gcn_b2,
    const float* __restrict__ q_w,  const float* __restrict__ q_b,
    const float* __restrict__ k_w,  const float* __restrict__ k_b,
    const float* __restrict__ v_w,  const float* __restrict__ v_b,
    const float* __restrict__ venue_t, const float* __restrict__ tour_t,
    const float* __restrict__ country_t, const float* __restrict__ fest_t,
    const float* __restrict__ mara_t,
    const float* __restrict__ ctx_w, const float* __restrict__ ctx_b,
    const float* __restrict__ p1_w,  const float* __restrict__ p1_b,
    const float* __restrict__ p2_w,  const float* __restrict__ p2_b,
    const float* __restrict__ p3_w,  const float* __restrict__ p3_b,
    float* __restrict__ out)
{
    const int b    = blockIdx.x;
    const int tid  = threadIdx.x;
    const int wv   = tid >> 6;
    const int lane = tid & 63;
    const int col0 = tid & 63;      // weight-staging column
    const int eq0  = tid >> 6;      // weight-staging e-quad

    __shared__ __align__(16) float xb0[MAXU][EMB];     // GCN state, in-place
    __shared__ __align__(16) float wldsT[2][EMB][WT];  // w1,w2 transposed; later k,v
    __shared__ __align__(16) float ctxw_l[56][EMB];
    __shared__ __align__(16) float qw_l[EMB][EMB];
    __shared__ __align__(16) float blds[2][EMB];
    __shared__ __align__(16) float bias_ctx[EMB], bias_q[EMB], bias_k[EMB], bias_v[EMB];
    __shared__ __align__(16) float bias_p1[128], bias_p2[EMB], bias_p3w[EMB];
    __shared__ float bias_p3b;
    __shared__ unsigned short idmap[N1];
    __shared__ int   sl[NPOS];
    __shared__ int   pmap[NPOS];
    __shared__ int   list_ids[MAXU];
    __shared__ float c_us[MAXU][NSHOW];
    __shared__ float occv[MAXU];
    __shared__ float invv[MAXU];
    __shared__ float cntm1[NSHOW];
    __shared__ float invc[NSHOW];
    __shared__ int   U_cnt;
    __shared__ __align__(16) float Xsum[NSHOW][EMB];
    __shared__ float XW[NSHOW][EMB];
    __shared__ float ctxin[56];
    __shared__ float ctxv[EMB];
    __shared__ float qv[EMB];
    __shared__ float vatt[NSHOW][EMB];
    __shared__ float attnw[NSHOW];
    __shared__ float hbuf[3 * EMB];
    __shared__ float h1b[128];
    __shared__ float partial[NT];

    // ======== P0: ALL early global loads; init; stage to LDS ========
    float w1r[4], w2r[4];
    #pragma unroll
    for (int j = 0; j < 4; j++) w1r[j] = gcn_w1[(eq0 * 4 + j) * EMB + col0];
    #pragma unroll
    for (int j = 0; j < 4; j++) w2r[j] = gcn_w2[(eq0 * 4 + j) * EMB + col0];
    const float4 qw4 = ((const float4*)q_w)[tid];
    float4 cw4 = make_float4(0.f, 0.f, 0.f, 0.f);
    if (tid < 896) cw4 = ((const float4*)ctx_w)[tid];
    float4 bb;
    if (tid < 32) bb = (tid < 16) ? ((const float4*)gcn_b1)[tid]
                                  : ((const float4*)gcn_b2)[tid - 16];
    const int slr = (tid < NPOS) ? prev_setlists[b * NPOS + tid] : 0;
    const int sid    = song_ids[b];
    const int vid    = venue_ids[b];
    const int tourid = tour_ids[b];
    const int cid    = country_ids[b];
    const int fid    = is_festival[b];
    const int mid    = is_marathon[b];

    for (int i = tid; i < N1; i += NT) idmap[i] = 0xFFFFu;
    if (tid < MAXU * NSHOW) ((float*)c_us)[tid] = 0.f;
    if (tid < NPOS) sl[tid] = slr;
    if (tid == 0) U_cnt = 0;
    *(float4*)&wldsT[0][col0][eq0 * 4] = make_float4(w1r[0], w1r[1], w1r[2], w1r[3]);
    *(float4*)&wldsT[1][col0][eq0 * 4] = make_float4(w2r[0], w2r[1], w2r[2], w2r[3]);
    ((float4*)qw_l)[tid] = qw4;
    if (tid < 896) ((float4*)ctxw_l)[tid] = cw4;
    if (tid < 32) ((float4*)blds)[tid] = bb;
    {
        int r = tid - 256;
        if (r >= 0 && r < 16)        ((float4*)bias_ctx)[r]       = ((const float4*)ctx_b)[r];
        else if (r >= 16 && r < 32)  ((float4*)bias_q)[r - 16]    = ((const float4*)q_b)[r - 16];
        else if (r >= 32 && r < 48)  ((float4*)bias_k)[r - 32]    = ((const float4*)k_b)[r - 32];
        else if (r >= 48 && r < 64)  ((float4*)bias_v)[r - 48]    = ((const float4*)v_b)[r - 48];
        else if (r >= 64 && r < 96)  ((float4*)bias_p1)[r - 64]   = ((const float4*)p1_b)[r - 64];
        else if (r >= 96 && r < 112) ((float4*)bias_p2)[r - 96]   = ((const float4*)p2_b)[r - 96];
        else if (r >= 112 && r < 128)((float4*)bias_p3w)[r - 112] = ((const float4*)p3_w)[r - 112];
        else if (r == 128)           bias_p3b = p3_b[0];
    }
    __syncthreads();   // B1

    // ======== P1: mark ids | cnt_show | ctxin embed gathers ========
    if (tid < NPOS) { int id = sl[tid]; if (id > 0) idmap[id] = 1u; }
    if (tid == NPOS) idmap[sid] = 1u;
    if (tid >= 128 && tid < 128 + NSHOW) {
        int s = tid - 128, c = 0;
        for (int i = 0; i < MSONG; i++) c += (sl[s * MSONG + i] > 0) ? 1 : 0;
        cntm1[s] = (float)(c - 1);
        invc[s] = 1.f / fmaxf((float)c, 1.f);
    }
    if (tid >= 144 && tid < 200) {
        int e = tid - 144; float val;
        if (e < 16)      val = venue_t[vid * 16 + e];
        else if (e < 32) val = tour_t[tourid * 16 + (e - 16)];
        else if (e < 40) val = country_t[cid * 8 + (e - 32)];
        else if (e < 48) val = fest_t[fid * 8 + (e - 40)];
        else             val = mara_t[mid * 8 + (e - 48)];
        ctxin[e] = val;
    }
    __syncthreads();   // B2

    // ======== P2: ballot compaction ========
    for (int i = tid; i < N1; i += NT) {
        const bool p = (idmap[i] == 1u);
        const unsigned long long m = __ballot(p);
        int base = 0;
        if (lane == 0) { int c = __popcll(m); if (c) base = atomicAdd(&U_cnt, c); }
        base = __shfl(base, 0, 64);
        if (p) {
            int r = __popcll(m & ((1ull << lane) - 1ull));
            int u = base + r;
            idmap[i] = (unsigned short)u;
            list_ids[u] = i;
        }
    }
    __syncthreads();   // B3
    const int U = U_cnt;   // <= 126

    // ======== P3: pmap + c_us | ctx matmul (LDS weights) | x0 gather ========
    if (tid < NPOS) {
        int id = sl[tid];
        int pm = (id > 0) ? (int)idmap[id] : -1;
        pmap[tid] = pm;
        if (pm >= 0) atomicAdd(&c_us[pm][tid / MSONG], 1.f);
    }
    if (tid >= 896 && tid < 960) {
        int c = tid - 896;
        float acc = bias_ctx[c];
        #pragma unroll
        for (int e = 0; e < 56; e++) acc += ctxin[e] * ctxw_l[e][c];
        ctxv[c] = acc;
    }
    for (int t = tid; t < MAXU * (EMB / 4); t += NT) {
        int u = t >> 4, e4 = t & 15;
        float4 v = make_float4(0.f, 0.f, 0.f, 0.f);
        if (u < U) v = ((const float4*)(song_emb + list_ids[u] * EMB))[e4];
        *(float4*)&xb0[u][e4 * 4] = v;
    }
    __syncthreads();   // B4

    // ======== P4: occ/inv | q (LDS weights) | Xsum-L0 from xb0 ========
    if (tid < MAXU) {
        float o = 0.f, r = 0.f;
        #pragma unroll
        for (int s = 0; s < NSHOW; s++) { float cc = c_us[tid][s]; o += cc; r += cc * cntm1[s]; }
        occv[tid] = o; invv[tid] = 1.f / (r + 1e-10f);
    }
    if (tid >= 128 && tid < 192) {
        int c = tid - 128;
        float acc = bias_q[c];
        #pragma unroll
        for (int e = 0; e < EMB; e++) acc += ctxv[e] * qw_l[e][c];
        qv[c] = acc;
    }
    if (wv >= 6 && wv < 11) {
        int s = wv - 6;
        int pm[MSONG];
        #pragma unroll
        for (int i = 0; i < MSONG; i++) pm[i] = pmap[s * MSONG + i];
        float acc = 0.f;
        #pragma unroll
        for (int i = 0; i < MSONG; i++) if (pm[i] >= 0) acc += xb0[pm[i]][lane];
        Xsum[s][lane] = acc;
    }
    __syncthreads();   // B5

    // ======== P5: XW-L0 ========
    if (tid < NSHOW * EMB) {
        int s = tid >> 6, c = tid & 63;
        float acc = 0.f;
        #pragma unroll 4
        for (int e4 = 0; e4 < 16; e4++) {
            const float4 w4 = *(const float4*)&wldsT[0][c][e4 * 4];
            const float4 xs = *(const float4*)&Xsum[s][e4 * 4];
            acc += w4.x * xs.x + w4.y * xs.y + w4.z * xs.z + w4.w * xs.w;
        }
        XW[s][c] = acc;
    }
    __syncthreads();   // B6

    // Each wave owns rows u ≡ wv (mod 16): reads/writes only its rows -> in-place safe.
    #define GCN_BODY(L)                                                          \
    {                                                                            \
        const float bias = blds[L][lane];                                        \
        float y[8];                                                              \
        _Pragma("unroll")                                                        \
        for (int uu = 0; uu < 8; ++uu) y[uu] = 0.f;                              \
        _Pragma("unroll 4")                                                      \
        for (int e4 = 0; e4 < 16; ++e4) {                                        \
            float4 a[8];                                                         \
            _Pragma("unroll")                                                    \
            for (int uu = 0; uu < 8; ++uu)                                       \
                a[uu] = *(const float4*)&xb0[(uu << 4) | wv][e4 * 4];            \
            const float4 w4 = *(const float4*)&wldsT[L][lane][e4 * 4];           \
            _Pragma("unroll")                                                    \
            for (int uu = 0; uu < 8; ++uu)                                       \
                y[uu] += a[uu].x * w4.x + a[uu].y * w4.y                         \
                       + a[uu].z * w4.z + a[uu].w * w4.w;                        \
        }                                                                        \
        _Pragma("unroll")                                                        \
        for (int uu = 0; uu < 8; ++uu) {                                         \
            const int u = (uu << 4) | wv;                                        \
            float acc = c_us[u][0] * XW[0][lane] + c_us[u][1] * XW[1][lane]      \
                      + c_us[u][2] * XW[2][lane] + c_us[u][3] * XW[3][lane]      \
                      + c_us[u][4] * XW[4][lane];                                \
            float val = (acc - occv[u] * y[uu]) * invv[u] + bias;                \
            xb0[u][lane] = fmaxf(val, 0.f);                                      \
        }                                                                        \
    }

    // ======== P6: GCN layer 0 ========
    GCN_BODY(0)
    __syncthreads();   // B7

    // ======== P7: Xsum-L1 | k restage into wldsT[0] (dead after P5/P6) ========
    {
        float kr[4];
        #pragma unroll
        for (int j = 0; j < 4; j++) kr[j] = k_w[(eq0 * 4 + j) * EMB + col0];
        if (wv >= 6 && wv < 11) {
            int s = wv - 6;
            int pm[MSONG];
            #pragma unroll
            for (int i = 0; i < MSONG; i++) pm[i] = pmap[s * MSONG + i];
            float acc = 0.f;
            #pragma unroll
            for (int i = 0; i < MSONG; i++) if (pm[i] >= 0) acc += xb0[pm[i]][lane];
            Xsum[s][lane] = acc;
        }
        *(float4*)&wldsT[0][col0][eq0 * 4] = make_float4(kr[0], kr[1], kr[2], kr[3]);
    }
    __syncthreads();   // B8

    // ======== P8: XW-L1 (wldsT[1] still w2) ========
    if (tid < NSHOW * EMB) {
        int s = tid >> 6, c = tid & 63;
        float acc = 0.f;
        #pragma unroll 4
        for (int e4 = 0; e4 < 16; e4++) {
            const float4 w4 = *(const float4*)&wldsT[1][c][e4 * 4];
            const float4 xs = *(const float4*)&Xsum[s][e4 * 4];
            acc += w4.x * xs.x + w4.y * xs.y + w4.z * xs.z + w4.w * xs.w;
        }
        XW[s][c] = acc;
    }
    __syncthreads();   // B9

    // ======== P9: GCN layer 1 + issue v load (write deferred past B10) ========
    float vr[4];
    #pragma unroll
    for (int j = 0; j < 4; j++) vr[j] = v_w[(eq0 * 4 + j) * EMB + col0];
    GCN_BODY(1)
    __syncthreads();   // B10

    // ======== P10: v restage | show sums | hbuf cand+ctx | p1/p2 prefetch ========
    *(float4*)&wldsT[1][col0][eq0 * 4] = make_float4(vr[0], vr[1], vr[2], vr[3]);
    const int kk1 = tid >> 7, o1 = tid & 127;
    const int kk2 = tid >> 6, o2 = lane;
    float p1wr[24], p2wr[8];
    #pragma unroll
    for (int j = 0; j < 24; j++) p1wr[j] = p1_w[(kk1 * 24 + j) * 128 + o1];
    #pragma unroll
    for (int j = 0; j < 8; j++)  p2wr[j] = p2_w[(kk2 * 8 + j) * 64 + o2];

    if (wv >= 6 && wv < 11) {   // show SUMS (invc applied in K/V phase)
        int s = wv - 6;
        int pm[MSONG];
        #pragma unroll
        for (int i = 0; i < MSONG; i++) pm[i] = pmap[s * MSONG + i];
        float acc = 0.f;
        #pragma unroll
        for (int i = 0; i < MSONG; i++) if (pm[i] >= 0) acc += xb0[pm[i]][lane];
        Xsum[s][lane] = acc;
    }
    if (tid < 64)                    hbuf[tid] = xb0[(int)idmap[sid]][tid];
    else if (tid >= 64 && tid < 128) hbuf[tid] = ctxv[tid - 64];
    __syncthreads();   // B11

    // ======== P11: K·q -> scores (waves 0-4) | V (waves 5-9) ========
    if (wv < NSHOW) {
        float s0 = 0.f;
        #pragma unroll 4
        for (int e4 = 0; e4 < 16; e4++) {
            const float4 w4 = *(const float4*)&wldsT[0][lane][e4 * 4];
            const float4 xs = *(const float4*)&Xsum[wv][e4 * 4];
            s0 += w4.x * xs.x + w4.y * xs.y + w4.z * xs.z + w4.w * xs.w;
        }
        float kk = s0 * invc[wv] + bias_k[lane];
        float p = kk * qv[lane];
        #pragma unroll
        for (int o = 32; o > 0; o >>= 1) p += __shfl_xor(p, o, 64);
        if (lane == 0) attnw[wv] = p * 0.125f;
    }
    if (wv >= 5 && wv < 10) {
        int s = wv - 5;
        float s0 = 0.f;
        #pragma unroll 4
        for (int e4 = 0; e4 < 16; e4++) {
            const float4 w4 = *(const float4*)&wldsT[1][lane][e4 * 4];
            const float4 xs = *(const float4*)&Xsum[s][e4 * 4];
            s0 += w4.x * xs.x + w4.y * xs.y + w4.z * xs.z + w4.w * xs.w;
        }
        vatt[s][lane] = s0 * invc[s] + bias_v[lane];
    }
    __syncthreads();   // B12

    // ======== P12: wave0 per-lane softmax + attended ========
    if (wv == 0) {
        float a0 = attnw[0], a1 = attnw[1], a2 = attnw[2], a3 = attnw[3], a4 = attnw[4];
        float mx = fmaxf(fmaxf(fmaxf(a0, a1), fmaxf(a2, a3)), a4);
        float e0 = expf(a0 - mx), e1 = expf(a1 - mx), e2 = expf(a2 - mx),
              e3 = expf(a3 - mx), e4 = expf(a4 - mx);
        float isum = 1.f / (e0 + e1 + e2 + e3 + e4);
        float att = (e0 * vatt[0][lane] + e1 * vatt[1][lane] + e2 * vatt[2][lane]
                   + e3 * vatt[3][lane] + e4 * vatt[4][lane]) * isum;
        hbuf[2 * EMB + lane] = att;
    }
    __syncthreads();   // B13

    // ======== P13: p1 partial (split-k 8) ========
    {
        float acc = (kk1 == 0) ? bias_p1[o1] : 0.f;
        #pragma unroll
        for (int j = 0; j < 24; j++) acc += hbuf[kk1 * 24 + j] * p1wr[j];
        partial[tid] = acc;
    }
    __syncthreads();   // B14

    // ======== P14: p1 reduce ========
    if (tid < 128) {
        float acc = 0.f;
        #pragma unroll
        for (int kk = 0; kk < 8; kk++) acc += partial[kk * 128 + tid];
        h1b[tid] = fmaxf(acc, 0.f);
    }
    __syncthreads();   // B15

    // ======== P15: p2 partial (split-k 16) ========
    {
        float acc = (kk2 == 0) ? bias_p2[o2] : 0.f;
        #pragma unroll
        for (int j = 0; j < 8; j++) acc += h1b[kk2 * 8 + j] * p2wr[j];
        partial[tid] = acc;
    }
    __syncthreads();   // B16

    // ======== P16: wave0 p2 reduce + p3 + sigmoid ========
    if (wv == 0) {
        float acc = 0.f;
        #pragma unroll
        for (int kk = 0; kk < 16; kk++) acc += partial[kk * 64 + lane];
        float h2 = fmaxf(acc, 0.f);
        float p = h2 * bias_p3w[lane];
        #pragma unroll
        for (int o = 32; o > 0; o >>= 1) p += __shfl_xor(p, o, 64);
        if (lane == 0) out[b] = 1.f / (1.f + expf(-(p + bias_p3b)));
    }
}

extern "C" void kernel_launch(void* const* d_in, const int* in_sizes, int n_in,
                              void* d_out, int out_size, void* d_ws, size_t ws_size,
                              hipStream_t stream) {
    (void)n_in; (void)out_size; (void)d_ws; (void)ws_size;
    const int B = in_sizes[0];
    setsgnn_kernel<<<B, NT, 0, stream>>>(
        (const int*)d_in[0], (const int*)d_in[1], (const int*)d_in[2],
        (const int*)d_in[3], (const int*)d_in[4], (const int*)d_in[5],
        (const int*)d_in[6],
        (const float*)d_in[7],
        (const float*)d_in[8],  (const float*)d_in[9],
        (const float*)d_in[10], (const float*)d_in[11],
        (const float*)d_in[12], (const float*)d_in[13],
        (const float*)d_in[14], (const float*)d_in[15],
        (const float*)d_in[16], (const float*)d_in[17],
        (const float*)d_in[18], (const float*)d_in[19],
        (const float*)d_in[20], (const float*)d_in[21],
        (const float*)d_in[22],
        (const float*)d_in[23], (const float*)d_in[24],
        (const float*)d_in[25], (const float*)d_in[26],
        (const float*)d_in[27], (const float*)d_in[28],
        (const float*)d_in[29], (const float*)d_in[30],
        (float*)d_out);
}